// Round 17
// baseline (126.388 us; speedup 1.0000x reference)
//
#include <hip/hip_runtime.h>
#include <hip/hip_bf16.h>
#include <math.h>

#define H 120
#define W 216
#define C 256
#define NPIX (H*W)
#define PATCH 13
#define PP 169
#define RAD 6
#define TOPKN 36
#define OBJ 11
#define MD 4
#define CW 344   // padded corr row stride (338 -> 344)
#define MW (W*MD)            // 864
#define MPLANE (H*MD*W*MD)   // 414720 floats per object plane

typedef unsigned short ushort;
typedef unsigned int   uint;
typedef __attribute__((ext_vector_type(8))) __bf16 bf16x8;
typedef __attribute__((ext_vector_type(4))) float   f32x4;

#define PLANE_B ((size_t)NPIX * 512)   // bytes per hi/lo plane of a transposed tensor

// corr tile geometry
#define YT 8                    // y rows per block
#define RT 20                   // staged fm rows = YT + 12
#define XT 16                   // x cols per block (one M tile)
#define UW 32                   // u window = XT + 16
#define PXS 128                 // staged px stride: 2 planes x 64B, XOR-swizzled reads
#define ROWS (UW * PXS)         // 4096 B per staged row
#define BUFB (RT * ROWS)        // 81920 B per buffer
#define NXT 14                  // ceil(216/16)
#define NYT 15                  // 120/8
#define NWG2 (NXT * NYT)        // 210 blocks (both frames per block)

__device__ inline ushort f2bf_rne(float x) {
  uint u = __float_as_uint(x);
  uint r = (u + 0x7FFFu + ((u >> 16) & 1u)) >> 16;
  return (ushort)r;
}
__device__ inline float bf2f(ushort h) { return __uint_as_float(((uint)h) << 16); }

// ---------------- kernel 0: transpose + hi/lo bf16 split (fm0/fm1 only; fq dropped) ----------------
__global__ __launch_bounds__(256) void k_prep(const float* __restrict__ fm0, const float* __restrict__ fm1,
                      char* fm0t, char* fm1t) {
  const float* src = (blockIdx.z == 0) ? fm0 : fm1;
  char* dst = (blockIdx.z == 0) ? fm0t : fm1t;

  const int p0 = blockIdx.x * 64;
  const int c0 = blockIdx.y * 64;
  const int tid = threadIdx.x;

  __shared__ float ts[64 * 65];
  {
    int p = tid & 63, cl = tid >> 6;
    #pragma unroll
    for (int jj = 0; jj < 16; ++jj) {
      int c = 4 * jj + cl;
      ts[c * 65 + p] = src[(size_t)(c0 + c) * NPIX + p0 + p];
    }
  }
  __syncthreads();
  {
    int pl = tid >> 2, sub = tid & 3;
    ushort hb[16], lb[16];
    #pragma unroll
    for (int i = 0; i < 16; ++i) {
      float x = ts[(sub * 16 + i) * 65 + pl];
      ushort h = f2bf_rne(x);
      hb[i] = h;
      lb[i] = f2bf_rne(x - bf2f(h));
    }
    size_t off = (size_t)(p0 + pl) * 512 + (size_t)c0 * 2 + sub * 32;
    *(uint4*)(dst + off)            = ((uint4*)hb)[0];
    *(uint4*)(dst + off + 16)       = ((uint4*)hb)[1];
    *(uint4*)(dst + PLANE_B + off)      = ((uint4*)lb)[0];
    *(uint4*)(dst + PLANE_B + off + 16) = ((uint4*)lb)[1];
  }
}

// ---------------- kernel 2 (MFMA; A built from raw fq in-register) ----------------
// R14/R16 structure; A fragments now: 8 strided f32 loads (L2-hot) + identical
// f2bf_rne hi/lo split done in-kernel -> Ah/Al bit-identical -> corr bit-identical.
// cF/nF f32x8 replace the old uint4 pairs: net-zero live registers (spill tripwire:
// WRITE_SIZE must stay ~36MB).
__global__ __launch_bounds__(1024, 4) void k_corr_mfma(const float* __restrict__ fq,
                        const char* __restrict__ fm0t, const char* __restrict__ fm1t,
                        float* __restrict__ corr) {
  // bijective XCD swizzle: 210 = 8*26 + 2
  int b = blockIdx.x;
  int xcd = b & 7, idx = b >> 3;
  int wgid = (xcd < 2) ? xcd * 27 + idx : 54 + (xcd - 2) * 26 + idx;
  int yt   = wgid % NYT;
  int xt   = wgid / NYT;

  const int y0 = yt * YT;
  const int X0 = xt * XT;
  const int tid  = threadIdx.x;
  const int wv   = tid >> 6;           // wave id 0..15
  const int wyy  = wv >> 1;            // y offset in tile 0..7
  const int nt   = wv & 1;             // u group
  const int lane = tid & 63;
  const int l15  = lane & 15, l4 = lane >> 4;
  const int y    = y0 + wyy;

  __shared__ __align__(16) char bsm[2 * BUFB];   // 163840 B

  uint soff[5];
  uint ldst;
  #pragma unroll
  for (int i = 0; i < 5; ++i) {
    int gdest = wv * 64 + lane + 1024 * i;
    int ri  = gdest >> 8;          // 0..19
    int rem = gdest & 255;
    int px  = rem >> 3;            // 0..31
    int pqp = rem & 7;
    int pqs = pqp ^ (px & 7);      // source (p,q) granule (rule #21 inverse swizzle)
    int p   = pqs >> 2, q = pqs & 3;
    int r = y0 - 6 + ri;  r = (r < 0) ? 0 : (r >= H ? H - 1 : r);
    int u = X0 - 8 + px;  u = (u < 0) ? 0 : (u >= W ? W - 1 : u);
    soff[i] = (uint)((size_t)p * PLANE_B + (size_t)(r * W + u) * 512 + q * 16);
  }
  ldst = (uint)(wv * 1024 + lane * 16);

  int xA = X0 + l15;
  const float* paf = fq + (size_t)(y * W + (xA < W ? xA : W - 1));  // + ch*NPIX per load

  const int pxn = 16 * nt + l15;
  const uint sw  = (uint)((l15 & 7) << 4);
  const uint bh_off = (uint)((pxn * PXS +      l4 * 16) ^ sw);
  const uint bl_off = (uint)((pxn * PXS + 64 + l4 * 16) ^ sw);

  int u0 = X0 + 16 * nt + l15 - 8;
  bool uok = (u0 >= 0) && (u0 < W);

  f32x4 acc[13];
  #pragma unroll
  for (int di = 0; di < 13; ++di) acc[di] = (f32x4){0.f, 0.f, 0.f, 0.f};

  auto STAGE = [&](int buf, const char* fb, int kn) {
    #pragma unroll
    for (int i = 0; i < 5; ++i)
      __builtin_amdgcn_global_load_lds(
        (const __attribute__((address_space(1))) void*)(fb + soff[i] + kn * 64),
        (__attribute__((address_space(3))) void*)(bsm + buf * BUFB + ldst + i * 16384),
        16, 0, 0);
  };

  STAGE(0, fm0t, 0);
  // A prologue: kc=0 channels (l4 octet) as raw f32
  float cF[8], nF[8];
  #pragma unroll
  for (int i = 0; i < 8; ++i)
    cF[i] = paf[(size_t)(l4 * 8 + i) * NPIX];
  __syncthreads();   // buf0 ready

  #pragma unroll
  for (int fi = 0; fi < 2; ++fi) {
    #pragma unroll
    for (int kc = 0; kc < 8; ++kc) {
      int t = fi * 8 + kc;
      if (t < 15) {
        const char* sfb = (t < 7) ? fm0t : fm1t;   // frame of step t+1
        int kn = (kc + 1) & 7;
        STAGE((kc + 1) & 1, sfb, kn);              // flies under this step's compute
        #pragma unroll
        for (int i = 0; i < 8; ++i)
          nF[i] = paf[(size_t)(kn * 32 + l4 * 8 + i) * NPIX];
      }
      const char* bb = bsm + (kc & 1) * BUFB;

      // in-register hi/lo split (identical math to old prep -> bit-identical fragments)
      ushort hb[8], lb[8];
      #pragma unroll
      for (int i = 0; i < 8; ++i) {
        ushort h = f2bf_rne(cF[i]);
        hb[i] = h;
        lb[i] = f2bf_rne(cF[i] - bf2f(h));
      }
      uint uh[4], ul[4];
      #pragma unroll
      for (int j = 0; j < 4; ++j) {
        uh[j] = (uint)hb[2*j] | ((uint)hb[2*j+1] << 16);
        ul[j] = (uint)lb[2*j] | ((uint)lb[2*j+1] << 16);
      }
      bf16x8 Ahv = __builtin_bit_cast(bf16x8, *(uint4*)uh);
      bf16x8 Alv = __builtin_bit_cast(bf16x8, *(uint4*)ul);

      #pragma unroll
      for (int di = 0; di < 13; ++di) {
        int rr = y + di - RAD;
        if (rr >= 0 && rr < H) {                   // wave-uniform
          const char* rb = bb + (wyy + di) * ROWS;
          bf16x8 Bhv = *(const bf16x8*)(rb + bh_off);
          bf16x8 Blv = *(const bf16x8*)(rb + bl_off);
          acc[di] = __builtin_amdgcn_mfma_f32_16x16x32_bf16(Ahv, Bhv, acc[di], 0, 0, 0);
          acc[di] = __builtin_amdgcn_mfma_f32_16x16x32_bf16(Ahv, Blv, acc[di], 0, 0, 0);
          acc[di] = __builtin_amdgcn_mfma_f32_16x16x32_bf16(Alv, Bhv, acc[di], 0, 0, 0);
        }
      }
      #pragma unroll
      for (int i = 0; i < 8; ++i) cF[i] = nF[i];   // static rotate
      __syncthreads();                             // vmcnt drain + barrier
    }

    float* cb = corr + (size_t)(y * W) * CW + fi * PP;
    #pragma unroll
    for (int di = 0; di < 13; ++di) {
      #pragma unroll
      for (int j = 0; j < 4; ++j) {
        int m  = l4 * 4 + j;
        int x  = X0 + m;
        int dj = 16 * nt + l15 - m - 2;
        if (x < W && dj >= 0 && dj < PATCH)
          cb[(size_t)x * CW + di * PATCH + dj] = uok ? acc[di][j] * 0.0625f : 0.f;
      }
      acc[di] = (f32x4){0.f, 0.f, 0.f, 0.f};
    }
  }
}

// ---------------- kernel 2 fallback (VALU, R2-validated) ----------------
__global__ __launch_bounds__(64) void k_corr_valu(const float* __restrict__ fq,
                       const float* __restrict__ fm0, const float* __restrict__ fm1,
                       float* __restrict__ corr) {
  int b = blockIdx.x;
  int lb = (b & 7) * 390 + (b >> 3);
  int y   = lb / 26;
  int r26 = lb - y * 26;
  int f   = r26 / 13;
  int di  = r26 - f * 13;
  const int tid = threadIdx.x;
  const int xg  = tid;
  const int r   = y + di - RAD;

  float* corr_base = corr + (size_t)(y * W) * CW + (f * PP + di * PATCH);

  if (r < 0 || r >= H) {
    if (xg < 54) {
      float* cp = corr_base + (size_t)(4 * xg) * CW;
      #pragma unroll
      for (int sub = 0; sub < 4; ++sub) {
        #pragma unroll
        for (int dj = 0; dj < PATCH; ++dj) cp[(size_t)sub * CW + dj] = 0.f;
      }
    }
    return;
  }

  const float* fm = f ? fm1 : fm0;
  __shared__ float fm_s[4 * 232];

  const float* pf[4];
  int  ldsoff[4];
  bool sval[4], mval[4];
  #pragma unroll
  for (int s = 0; s < 4; ++s) {
    int i = tid + 64 * s;
    sval[s] = (i < 232);
    int ii = sval[s] ? i : 0;
    int ch = ii / 58;
    int m  = ii - ch * 58;
    int x  = 4 * m - 8;
    mval[s] = sval[s] && (m >= 2) && (m <= 55);
    ldsoff[s] = ch * 232 + 4 * m;
    pf[s] = fm + (size_t)ch * NPIX + (size_t)r * W + (mval[s] ? x : 0);
  }

  const float* pq = fq + (size_t)y * W + 4 * ((xg < 54) ? xg : 0);

  float4 acc[PATCH];
  #pragma unroll
  for (int d = 0; d < PATCH; ++d) acc[d] = make_float4(0.f, 0.f, 0.f, 0.f);

  for (int c0 = 0; c0 < C; c0 += 4) {
    #pragma unroll
    for (int s = 0; s < 4; ++s) {
      if (sval[s]) {
        float4 v = make_float4(0.f, 0.f, 0.f, 0.f);
        if (mval[s]) v = *(const float4*)(pf[s]);
        *(float4*)&fm_s[ldsoff[s]] = v;
        pf[s] += 4 * (size_t)NPIX;
      }
    }
    __syncthreads();
    if (xg < 54) {
      #pragma unroll
      for (int ch = 0; ch < 4; ++ch) {
        float4 q4 = *(const float4*)(pq + (size_t)ch * NPIX);
        float rv[20];
        #pragma unroll
        for (int qq = 0; qq < 5; ++qq) {
          float4 t4 = *(const float4*)&fm_s[ch * 232 + 4 * xg + 4 * qq];
          rv[4*qq+0] = t4.x; rv[4*qq+1] = t4.y; rv[4*qq+2] = t4.z; rv[4*qq+3] = t4.w;
        }
        #pragma unroll
        for (int dj = 0; dj < PATCH; ++dj) {
          acc[dj].x += q4.x * rv[dj + 2];
          acc[dj].y += q4.y * rv[dj + 3];
          acc[dj].z += q4.z * rv[dj + 4];
          acc[dj].w += q4.w * rv[dj + 5];
        }
      }
      pq += 4 * (size_t)NPIX;
    }
    __syncthreads();
  }

  if (xg < 54) {
    float* cp = corr_base + (size_t)(4 * xg) * CW;
    #pragma unroll
    for (int dj = 0; dj < PATCH; ++dj) {
      cp[dj]                  = acc[dj].x * 0.0625f;
      cp[(size_t)1 * CW + dj] = acc[dj].y * 0.0625f;
      cp[(size_t)2 * CW + dj] = acc[dj].z * 0.0625f;
      cp[(size_t)3 * CW + dj] = acc[dj].w * 0.0625f;
    }
  }
}

// ---------------- kernel 3: top-36 two-level rank select + fused mask gather (R16-validated) ----------------
__global__ __launch_bounds__(256) void k_topk(const float* __restrict__ corr,
                       const float* __restrict__ m0, const float* __restrict__ m1,
                       float* __restrict__ out) {
  int wid = (blockIdx.x * 256 + threadIdx.x) >> 6;
  int lane = threadIdx.x & 63;
  if (wid >= NPIX) return;
  const float* cr = corr + (size_t)wid * CW;

  float v[6]; uint ui[6];
  #pragma unroll
  for (int s = 0; s < 6; ++s) {
    int idx = lane + 64 * s;
    bool ok = idx < 2 * PP;
    float f = ok ? cr[idx] : 0.f;
    v[s] = f;
    uint bb = __float_as_uint(f);
    uint u = bb ^ (uint)(((int)bb >> 31) | 0x80000000);
    ui[s] = ok ? u : 0u;
  }

  uint lo = 0u, hi = 0xFFFFu;
  for (int it = 0; it < 16; ++it) {
    uint mid = (lo + hi) >> 1;
    int c = 0;
    #pragma unroll
    for (int s = 0; s < 6; ++s)
      c += __popcll(__ballot((ui[s] >> 16) > mid));
    if (c <= 35) hi = mid; else lo = mid + 1;
  }
  const uint k16 = lo;

  int g = 0, e = 0;
  #pragma unroll
  for (int s = 0; s < 6; ++s) {
    g += __popcll(__ballot((ui[s] >> 16) > k16));
    e += __popcll(__ballot((ui[s] >> 16) == k16));
  }
  const int need = 36 - g;

  float w[6];
  float zp = 0.f;

  if (e == need) {
    uint x0 = k16 << 16;
    uint tb = (x0 & 0x80000000u) ? (x0 ^ 0x80000000u) : ~x0;
    const float tf = __uint_as_float(tb);
    #pragma unroll
    for (int s = 0; s < 6; ++s) {
      bool a = (ui[s] >> 16) >= k16;
      w[s] = a ? __expf(v[s] - tf) : 0.f;
      zp += w[s];
    }
  } else {
    uint l2 = k16 << 16, h2 = (k16 << 16) | 0xFFFFu;
    for (int it = 0; it < 16; ++it) {
      uint mid = l2 + ((h2 - l2) >> 1);
      int c = 0;
      #pragma unroll
      for (int s = 0; s < 6; ++s)
        c += __popcll(__ballot(ui[s] > mid));
      if (c <= 35) h2 = mid; else l2 = mid + 1;
    }
    const uint x0 = l2;
    int cgt = 0;
    #pragma unroll
    for (int s = 0; s < 6; ++s) cgt += __popcll(__ballot(ui[s] > x0));
    const int needT = 36 - cgt;
    uint tb = (x0 & 0x80000000u) ? (x0 ^ 0x80000000u) : ~x0;
    const float tf = __uint_as_float(tb);
    int prior = 0;
    #pragma unroll
    for (int s = 0; s < 6; ++s) {
      unsigned long long tie = __ballot(ui[s] == x0);
      uint below = __builtin_amdgcn_mbcnt_hi((uint)(tie >> 32),
                    __builtin_amdgcn_mbcnt_lo((uint)tie, 0u));
      bool a = (ui[s] > x0) || ((ui[s] == x0) && ((prior + (int)below) < needT));
      prior += __popcll(tie);
      w[s] = a ? __expf(v[s] - tf) : 0.f;
      zp += w[s];
    }
  }

  float Z = zp;
  #pragma unroll
  for (int off = 32; off >= 1; off >>= 1) Z += __shfl_xor(Z, off, 64);

  int y = wid / W, x = wid - (wid / W) * W;
  float no[OBJ];
  #pragma unroll
  for (int o = 0; o < OBJ; ++o) no[o] = 0.f;
  #pragma unroll
  for (int s = 0; s < 6; ++s) {
    if (w[s] > 0.f) {
      int idx = lane + 64 * s;
      int ff = idx >= PP;
      int r = idx - ff * PP;
      int di = r / PATCH, dj = r - (r / PATCH) * PATCH;
      int yy = y + di - RAD, xx = x + dj - RAD;
      if (yy >= 0 && yy < H && xx >= 0 && xx < W) {
        const float* mb = (ff ? m1 : m0) + (size_t)(MD * yy) * MW + MD * xx;
        #pragma unroll
        for (int o = 0; o < OBJ; ++o) no[o] += w[s] * mb[(size_t)o * MPLANE];
      }
    }
  }
  float inv = 1.f / Z;
  #pragma unroll
  for (int o = 0; o < OBJ; ++o) {
    float pr = no[o];
    #pragma unroll
    for (int off = 32; off >= 1; off >>= 1) pr += __shfl_xor(pr, off, 64);
    if (lane == 0) out[(size_t)o * NPIX + wid] = pr * inv;
  }
}

extern "C" void kernel_launch(void* const* d_in, const int* in_sizes, int n_in,
                              void* d_out, int out_size, void* d_ws, size_t ws_size,
                              hipStream_t stream) {
  const float* fq  = (const float*)d_in[0];
  const float* fm0 = (const float*)d_in[1];
  const float* fm1 = (const float*)d_in[2];
  const float* m0  = (const float*)d_in[3];
  const float* m1  = (const float*)d_in[4];
  float* out = (float*)d_out;

  char* ws = (char*)d_ws;
  size_t off = 0;
  auto alloc = [&](size_t sz) { size_t o = off; off = (off + sz + 1023) & ~(size_t)1023; return o; };

  size_t corr_o = alloc((size_t)NPIX * CW * sizeof(float));
  size_t fm0t_o = alloc(2 * PLANE_B);
  size_t fm1t_o = alloc(2 * PLANE_B);
  size_t needed = off;

  float* corr = (float*)(ws + corr_o);

  if (ws_size >= needed) {
    char* fm0t = ws + fm0t_o;
    char* fm1t = ws + fm1t_o;
    dim3 gp(405, 4, 2);
    k_prep<<<gp, 256, 0, stream>>>(fm0, fm1, fm0t, fm1t);
    k_corr_mfma<<<NWG2, 1024, 0, stream>>>(fq, fm0t, fm1t, corr);
  } else {
    k_corr_valu<<<120 * 26, 64, 0, stream>>>(fq, fm0, fm1, corr);
  }

  k_topk<<<NPIX / 4, 256, 0, stream>>>(corr, m0, m1, out);
}

// Round 18
// 123.639 us; speedup vs baseline: 1.0222x; 1.0222x over previous
//
#include <hip/hip_runtime.h>
#include <hip/hip_bf16.h>
#include <math.h>

#define H 120
#define W 216
#define C 256
#define NPIX (H*W)
#define PATCH 13
#define PP 169
#define RAD 6
#define TOPKN 36
#define OBJ 11
#define MD 4
#define CW 344   // padded corr row stride (338 -> 344)
#define MW (W*MD)            // 864
#define MPLANE (H*MD*W*MD)   // 414720 floats per object plane

typedef unsigned short ushort;
typedef unsigned int   uint;
typedef __attribute__((ext_vector_type(8))) __bf16 bf16x8;
typedef __attribute__((ext_vector_type(4))) float   f32x4;

#define PLANE_B ((size_t)NPIX * 512)   // bytes per hi/lo plane of a transposed tensor

// corr tile geometry
#define YT 8                    // y rows per block
#define RT 20                   // staged fm rows = YT + 12
#define XT 16                   // x cols per block (one M tile)
#define UW 32                   // u window = XT + 16
#define PXS 128                 // staged px stride: 2 planes x 64B, XOR-swizzled reads
#define ROWS (UW * PXS)         // 4096 B per staged row
#define BUFB (RT * ROWS)        // 81920 B per buffer
#define NXT 14                  // ceil(216/16)
#define NYT 15                  // 120/8
#define NWG2 (NXT * NYT)        // 210 blocks (both frames per block)

__device__ inline ushort f2bf_rne(float x) {
  uint u = __float_as_uint(x);
  uint r = (u + 0x7FFFu + ((u >> 16) & 1u)) >> 16;
  return (ushort)r;
}
__device__ inline float bf2f(ushort h) { return __uint_as_float(((uint)h) << 16); }

// ---------------- kernel 0: transpose + hi/lo bf16 split (R14/R16-validated) ----------------
__global__ __launch_bounds__(256) void k_prep(const float* __restrict__ fq,
                      const float* __restrict__ fm0, const float* __restrict__ fm1,
                      char* fqt, char* fm0t, char* fm1t) {
  const float* src = (blockIdx.z == 0) ? fq : (blockIdx.z == 1) ? fm0 : fm1;
  char* dst = (blockIdx.z == 0) ? fqt : (blockIdx.z == 1) ? fm0t : fm1t;

  const int p0 = blockIdx.x * 64;
  const int c0 = blockIdx.y * 64;
  const int tid = threadIdx.x;

  __shared__ float ts[64 * 65];
  {
    int p = tid & 63, cl = tid >> 6;
    #pragma unroll
    for (int jj = 0; jj < 16; ++jj) {
      int c = 4 * jj + cl;
      ts[c * 65 + p] = src[(size_t)(c0 + c) * NPIX + p0 + p];
    }
  }
  __syncthreads();
  {
    int pl = tid >> 2, sub = tid & 3;
    ushort hb[16], lb[16];
    #pragma unroll
    for (int i = 0; i < 16; ++i) {
      float x = ts[(sub * 16 + i) * 65 + pl];
      ushort h = f2bf_rne(x);
      hb[i] = h;
      lb[i] = f2bf_rne(x - bf2f(h));
    }
    size_t off = (size_t)(p0 + pl) * 512 + (size_t)c0 * 2 + sub * 32;
    *(uint4*)(dst + off)            = ((uint4*)hb)[0];
    *(uint4*)(dst + off + 16)       = ((uint4*)hb)[1];
    *(uint4*)(dst + PLANE_B + off)      = ((uint4*)lb)[0];
    *(uint4*)(dst + PLANE_B + off + 16) = ((uint4*)lb)[1];
  }
}

// ---------------- kernel 2 (MFMA, R16-validated: light waves + both frames per block) ----------------
__global__ __launch_bounds__(1024, 4) void k_corr_mfma(const char* __restrict__ fqt,
                        const char* __restrict__ fm0t, const char* __restrict__ fm1t,
                        float* __restrict__ corr) {
  // bijective XCD swizzle: 210 = 8*26 + 2
  int b = blockIdx.x;
  int xcd = b & 7, idx = b >> 3;
  int wgid = (xcd < 2) ? xcd * 27 + idx : 54 + (xcd - 2) * 26 + idx;
  int yt   = wgid % NYT;
  int xt   = wgid / NYT;

  const int y0 = yt * YT;
  const int X0 = xt * XT;
  const int tid  = threadIdx.x;
  const int wv   = tid >> 6;           // wave id 0..15
  const int wyy  = wv >> 1;            // y offset in tile 0..7
  const int nt   = wv & 1;             // u group
  const int lane = tid & 63;
  const int l15  = lane & 15, l4 = lane >> 4;
  const int y    = y0 + wyy;

  __shared__ __align__(16) char bsm[2 * BUFB];   // 163840 B

  uint soff[5];
  uint ldst;
  #pragma unroll
  for (int i = 0; i < 5; ++i) {
    int gdest = wv * 64 + lane + 1024 * i;
    int ri  = gdest >> 8;          // 0..19
    int rem = gdest & 255;
    int px  = rem >> 3;            // 0..31
    int pqp = rem & 7;
    int pqs = pqp ^ (px & 7);      // source (p,q) granule (rule #21 inverse swizzle)
    int p   = pqs >> 2, q = pqs & 3;
    int r = y0 - 6 + ri;  r = (r < 0) ? 0 : (r >= H ? H - 1 : r);
    int u = X0 - 8 + px;  u = (u < 0) ? 0 : (u >= W ? W - 1 : u);
    soff[i] = (uint)((size_t)p * PLANE_B + (size_t)(r * W + u) * 512 + q * 16);
  }
  ldst = (uint)(wv * 1024 + lane * 16);

  int xA = X0 + l15;
  const char* pa = fqt + (size_t)(y * W + (xA < W ? xA : W - 1)) * 512 + l4 * 16;

  const int pxn = 16 * nt + l15;
  const uint sw  = (uint)((l15 & 7) << 4);
  const uint bh_off = (uint)((pxn * PXS +      l4 * 16) ^ sw);
  const uint bl_off = (uint)((pxn * PXS + 64 + l4 * 16) ^ sw);

  int u0 = X0 + 16 * nt + l15 - 8;
  bool uok = (u0 >= 0) && (u0 < W);

  f32x4 acc[13];
  #pragma unroll
  for (int di = 0; di < 13; ++di) acc[di] = (f32x4){0.f, 0.f, 0.f, 0.f};

  auto STAGE = [&](int buf, const char* fb, int kn) {
    #pragma unroll
    for (int i = 0; i < 5; ++i)
      __builtin_amdgcn_global_load_lds(
        (const __attribute__((address_space(1))) void*)(fb + soff[i] + kn * 64),
        (__attribute__((address_space(3))) void*)(bsm + buf * BUFB + ldst + i * 16384),
        16, 0, 0);
  };

  STAGE(0, fm0t, 0);
  uint4 aCh = *(const uint4*)(pa);
  uint4 aCl = *(const uint4*)(pa + PLANE_B);
  uint4 aNh, aNl;
  __syncthreads();   // buf0 ready

  #pragma unroll
  for (int fi = 0; fi < 2; ++fi) {
    #pragma unroll
    for (int kc = 0; kc < 8; ++kc) {
      int t = fi * 8 + kc;
      if (t < 15) {
        const char* sfb = (t < 7) ? fm0t : fm1t;   // frame of step t+1
        int kn = (kc + 1) & 7;
        STAGE((kc + 1) & 1, sfb, kn);              // flies under this step's compute
        aNh = *(const uint4*)(pa + kn * 64);
        aNl = *(const uint4*)(pa + PLANE_B + kn * 64);
      }
      const char* bb = bsm + (kc & 1) * BUFB;
      bf16x8 Ahv = __builtin_bit_cast(bf16x8, aCh);
      bf16x8 Alv = __builtin_bit_cast(bf16x8, aCl);

      #pragma unroll
      for (int di = 0; di < 13; ++di) {
        int rr = y + di - RAD;
        if (rr >= 0 && rr < H) {                   // wave-uniform
          const char* rb = bb + (wyy + di) * ROWS;
          bf16x8 Bhv = *(const bf16x8*)(rb + bh_off);
          bf16x8 Blv = *(const bf16x8*)(rb + bl_off);
          acc[di] = __builtin_amdgcn_mfma_f32_16x16x32_bf16(Ahv, Bhv, acc[di], 0, 0, 0);
          acc[di] = __builtin_amdgcn_mfma_f32_16x16x32_bf16(Ahv, Blv, acc[di], 0, 0, 0);
          acc[di] = __builtin_amdgcn_mfma_f32_16x16x32_bf16(Alv, Bhv, acc[di], 0, 0, 0);
        }
      }
      aCh = aNh; aCl = aNl;                        // static rotate
      __syncthreads();                             // vmcnt drain + barrier
    }

    float* cb = corr + (size_t)(y * W) * CW + fi * PP;
    #pragma unroll
    for (int di = 0; di < 13; ++di) {
      #pragma unroll
      for (int j = 0; j < 4; ++j) {
        int m  = l4 * 4 + j;
        int x  = X0 + m;
        int dj = 16 * nt + l15 - m - 2;
        if (x < W && dj >= 0 && dj < PATCH)
          cb[(size_t)x * CW + di * PATCH + dj] = uok ? acc[di][j] * 0.0625f : 0.f;
      }
      acc[di] = (f32x4){0.f, 0.f, 0.f, 0.f};
    }
  }
}

// ---------------- kernel 2 fallback (VALU, R2-validated) ----------------
__global__ __launch_bounds__(64) void k_corr_valu(const float* __restrict__ fq,
                       const float* __restrict__ fm0, const float* __restrict__ fm1,
                       float* __restrict__ corr) {
  int b = blockIdx.x;
  int lb = (b & 7) * 390 + (b >> 3);
  int y   = lb / 26;
  int r26 = lb - y * 26;
  int f   = r26 / 13;
  int di  = r26 - f * 13;
  const int tid = threadIdx.x;
  const int xg  = tid;
  const int r   = y + di - RAD;

  float* corr_base = corr + (size_t)(y * W) * CW + (f * PP + di * PATCH);

  if (r < 0 || r >= H) {
    if (xg < 54) {
      float* cp = corr_base + (size_t)(4 * xg) * CW;
      #pragma unroll
      for (int sub = 0; sub < 4; ++sub) {
        #pragma unroll
        for (int dj = 0; dj < PATCH; ++dj) cp[(size_t)sub * CW + dj] = 0.f;
      }
    }
    return;
  }

  const float* fm = f ? fm1 : fm0;
  __shared__ float fm_s[4 * 232];

  const float* pf[4];
  int  ldsoff[4];
  bool sval[4], mval[4];
  #pragma unroll
  for (int s = 0; s < 4; ++s) {
    int i = tid + 64 * s;
    sval[s] = (i < 232);
    int ii = sval[s] ? i : 0;
    int ch = ii / 58;
    int m  = ii - ch * 58;
    int x  = 4 * m - 8;
    mval[s] = sval[s] && (m >= 2) && (m <= 55);
    ldsoff[s] = ch * 232 + 4 * m;
    pf[s] = fm + (size_t)ch * NPIX + (size_t)r * W + (mval[s] ? x : 0);
  }

  const float* pq = fq + (size_t)y * W + 4 * ((xg < 54) ? xg : 0);

  float4 acc[PATCH];
  #pragma unroll
  for (int d = 0; d < PATCH; ++d) acc[d] = make_float4(0.f, 0.f, 0.f, 0.f);

  for (int c0 = 0; c0 < C; c0 += 4) {
    #pragma unroll
    for (int s = 0; s < 4; ++s) {
      if (sval[s]) {
        float4 v = make_float4(0.f, 0.f, 0.f, 0.f);
        if (mval[s]) v = *(const float4*)(pf[s]);
        *(float4*)&fm_s[ldsoff[s]] = v;
        pf[s] += 4 * (size_t)NPIX;
      }
    }
    __syncthreads();
    if (xg < 54) {
      #pragma unroll
      for (int ch = 0; ch < 4; ++ch) {
        float4 q4 = *(const float4*)(pq + (size_t)ch * NPIX);
        float rv[20];
        #pragma unroll
        for (int qq = 0; qq < 5; ++qq) {
          float4 t4 = *(const float4*)&fm_s[ch * 232 + 4 * xg + 4 * qq];
          rv[4*qq+0] = t4.x; rv[4*qq+1] = t4.y; rv[4*qq+2] = t4.z; rv[4*qq+3] = t4.w;
        }
        #pragma unroll
        for (int dj = 0; dj < PATCH; ++dj) {
          acc[dj].x += q4.x * rv[dj + 2];
          acc[dj].y += q4.y * rv[dj + 3];
          acc[dj].z += q4.z * rv[dj + 4];
          acc[dj].w += q4.w * rv[dj + 5];
        }
      }
      pq += 4 * (size_t)NPIX;
    }
    __syncthreads();
  }

  if (xg < 54) {
    float* cp = corr_base + (size_t)(4 * xg) * CW;
    #pragma unroll
    for (int dj = 0; dj < PATCH; ++dj) {
      cp[dj]                  = acc[dj].x * 0.0625f;
      cp[(size_t)1 * CW + dj] = acc[dj].y * 0.0625f;
      cp[(size_t)2 * CW + dj] = acc[dj].z * 0.0625f;
      cp[(size_t)3 * CW + dj] = acc[dj].w * 0.0625f;
    }
  }
}

// ---------------- kernel 3: top-36 rank select + fused gather, XCD-swizzled pixels ----------------
// R16-validated math; block->pixel mapping XCD-chunked (6480 = 8*810, bijective) so each
// XCD's L2 holds a contiguous mask slice (T1 mechanism: inter-block gather locality).
__global__ __launch_bounds__(256) void k_topk(const float* __restrict__ corr,
                       const float* __restrict__ m0, const float* __restrict__ m1,
                       float* __restrict__ out) {
  int bsw = (blockIdx.x & 7) * 810 + (blockIdx.x >> 3);   // XCD-chunked remap
  int wid = bsw * 4 + (threadIdx.x >> 6);
  int lane = threadIdx.x & 63;
  if (wid >= NPIX) return;
  const float* cr = corr + (size_t)wid * CW;

  float v[6]; uint ui[6];
  #pragma unroll
  for (int s = 0; s < 6; ++s) {
    int idx = lane + 64 * s;
    bool ok = idx < 2 * PP;
    float f = ok ? cr[idx] : 0.f;
    v[s] = f;
    uint bb = __float_as_uint(f);
    uint u = bb ^ (uint)(((int)bb >> 31) | 0x80000000);
    ui[s] = ok ? u : 0u;
  }

  uint lo = 0u, hi = 0xFFFFu;
  for (int it = 0; it < 16; ++it) {
    uint mid = (lo + hi) >> 1;
    int c = 0;
    #pragma unroll
    for (int s = 0; s < 6; ++s)
      c += __popcll(__ballot((ui[s] >> 16) > mid));
    if (c <= 35) hi = mid; else lo = mid + 1;
  }
  const uint k16 = lo;

  int g = 0, e = 0;
  #pragma unroll
  for (int s = 0; s < 6; ++s) {
    g += __popcll(__ballot((ui[s] >> 16) > k16));
    e += __popcll(__ballot((ui[s] >> 16) == k16));
  }
  const int need = 36 - g;

  float w[6];
  float zp = 0.f;

  if (e == need) {
    uint x0 = k16 << 16;
    uint tb = (x0 & 0x80000000u) ? (x0 ^ 0x80000000u) : ~x0;
    const float tf = __uint_as_float(tb);
    #pragma unroll
    for (int s = 0; s < 6; ++s) {
      bool a = (ui[s] >> 16) >= k16;
      w[s] = a ? __expf(v[s] - tf) : 0.f;
      zp += w[s];
    }
  } else {
    uint l2 = k16 << 16, h2 = (k16 << 16) | 0xFFFFu;
    for (int it = 0; it < 16; ++it) {
      uint mid = l2 + ((h2 - l2) >> 1);
      int c = 0;
      #pragma unroll
      for (int s = 0; s < 6; ++s)
        c += __popcll(__ballot(ui[s] > mid));
      if (c <= 35) h2 = mid; else l2 = mid + 1;
    }
    const uint x0 = l2;
    int cgt = 0;
    #pragma unroll
    for (int s = 0; s < 6; ++s) cgt += __popcll(__ballot(ui[s] > x0));
    const int needT = 36 - cgt;
    uint tb = (x0 & 0x80000000u) ? (x0 ^ 0x80000000u) : ~x0;
    const float tf = __uint_as_float(tb);
    int prior = 0;
    #pragma unroll
    for (int s = 0; s < 6; ++s) {
      unsigned long long tie = __ballot(ui[s] == x0);
      uint below = __builtin_amdgcn_mbcnt_hi((uint)(tie >> 32),
                    __builtin_amdgcn_mbcnt_lo((uint)tie, 0u));
      bool a = (ui[s] > x0) || ((ui[s] == x0) && ((prior + (int)below) < needT));
      prior += __popcll(tie);
      w[s] = a ? __expf(v[s] - tf) : 0.f;
      zp += w[s];
    }
  }

  float Z = zp;
  #pragma unroll
  for (int off = 32; off >= 1; off >>= 1) Z += __shfl_xor(Z, off, 64);

  int y = wid / W, x = wid - (wid / W) * W;
  float no[OBJ];
  #pragma unroll
  for (int o = 0; o < OBJ; ++o) no[o] = 0.f;
  #pragma unroll
  for (int s = 0; s < 6; ++s) {
    if (w[s] > 0.f) {
      int idx = lane + 64 * s;
      int ff = idx >= PP;
      int r = idx - ff * PP;
      int di = r / PATCH, dj = r - (r / PATCH) * PATCH;
      int yy = y + di - RAD, xx = x + dj - RAD;
      if (yy >= 0 && yy < H && xx >= 0 && xx < W) {
        const float* mb = (ff ? m1 : m0) + (size_t)(MD * yy) * MW + MD * xx;
        #pragma unroll
        for (int o = 0; o < OBJ; ++o) no[o] += w[s] * mb[(size_t)o * MPLANE];
      }
    }
  }
  float inv = 1.f / Z;
  #pragma unroll
  for (int o = 0; o < OBJ; ++o) {
    float pr = no[o];
    #pragma unroll
    for (int off = 32; off >= 1; off >>= 1) pr += __shfl_xor(pr, off, 64);
    if (lane == 0) out[(size_t)o * NPIX + wid] = pr * inv;
  }
}

extern "C" void kernel_launch(void* const* d_in, const int* in_sizes, int n_in,
                              void* d_out, int out_size, void* d_ws, size_t ws_size,
                              hipStream_t stream) {
  const float* fq  = (const float*)d_in[0];
  const float* fm0 = (const float*)d_in[1];
  const float* fm1 = (const float*)d_in[2];
  const float* m0  = (const float*)d_in[3];
  const float* m1  = (const float*)d_in[4];
  float* out = (float*)d_out;

  char* ws = (char*)d_ws;
  size_t off = 0;
  auto alloc = [&](size_t sz) { size_t o = off; off = (off + sz + 1023) & ~(size_t)1023; return o; };

  size_t corr_o = alloc((size_t)NPIX * CW * sizeof(float));
  size_t fqt_o  = alloc(2 * PLANE_B);
  size_t fm0t_o = alloc(2 * PLANE_B);
  size_t fm1t_o = alloc(2 * PLANE_B);
  size_t needed = off;

  float* corr = (float*)(ws + corr_o);

  if (ws_size >= needed) {
    char* fqt  = ws + fqt_o;
    char* fm0t = ws + fm0t_o;
    char* fm1t = ws + fm1t_o;
    dim3 gp(405, 4, 3);
    k_prep<<<gp, 256, 0, stream>>>(fq, fm0, fm1, fqt, fm0t, fm1t);
    k_corr_mfma<<<NWG2, 1024, 0, stream>>>(fqt, fm0t, fm1t, corr);
  } else {
    k_corr_valu<<<120 * 26, 64, 0, stream>>>(fq, fm0, fm1, corr);
  }

  k_topk<<<NPIX / 4, 256, 0, stream>>>(corr, m0, m1, out);
}

// Round 19
// 120.650 us; speedup vs baseline: 1.0476x; 1.0248x over previous
//
#include <hip/hip_runtime.h>
#include <hip/hip_bf16.h>
#include <math.h>

#define H 120
#define W 216
#define C 256
#define NPIX (H*W)
#define PATCH 13
#define PP 169
#define RAD 6
#define TOPKN 36
#define OBJ 11
#define MD 4
#define CW 344   // padded corr row stride (338 -> 344)
#define MW (W*MD)            // 864
#define MPLANE (H*MD*W*MD)   // 414720 floats per object plane

typedef unsigned short ushort;
typedef unsigned int   uint;
typedef __attribute__((ext_vector_type(8))) __bf16 bf16x8;
typedef __attribute__((ext_vector_type(4))) float   f32x4;

#define PLANE_B ((size_t)NPIX * 512)   // bytes per hi/lo plane of a transposed tensor

// corr tile geometry
#define YT 8                    // y rows per block
#define RT 20                   // staged fm rows = YT + 12
#define XT 16                   // x cols per block (one M tile)
#define UW 32                   // u window = XT + 16
#define PXS 128                 // staged px stride: 2 planes x 64B, XOR-swizzled reads
#define ROWS (UW * PXS)         // 4096 B per staged row
#define BUFB (RT * ROWS)        // 81920 B per buffer
#define NXT 14                  // ceil(216/16)
#define NYT 15                  // 120/8
#define NWG2 (NXT * NYT)        // 210 blocks (both frames per block)

__device__ inline ushort f2bf_rne(float x) {
  uint u = __float_as_uint(x);
  uint r = (u + 0x7FFFu + ((u >> 16) & 1u)) >> 16;
  return (ushort)r;
}
__device__ inline float bf2f(ushort h) { return __uint_as_float(((uint)h) << 16); }

// ---------------- kernel 0: transpose + hi/lo bf16 split (R14/R16-validated) ----------------
__global__ __launch_bounds__(256) void k_prep(const float* __restrict__ fq,
                      const float* __restrict__ fm0, const float* __restrict__ fm1,
                      char* fqt, char* fm0t, char* fm1t) {
  const float* src = (blockIdx.z == 0) ? fq : (blockIdx.z == 1) ? fm0 : fm1;
  char* dst = (blockIdx.z == 0) ? fqt : (blockIdx.z == 1) ? fm0t : fm1t;

  const int p0 = blockIdx.x * 64;
  const int c0 = blockIdx.y * 64;
  const int tid = threadIdx.x;

  __shared__ float ts[64 * 65];
  {
    int p = tid & 63, cl = tid >> 6;
    #pragma unroll
    for (int jj = 0; jj < 16; ++jj) {
      int c = 4 * jj + cl;
      ts[c * 65 + p] = src[(size_t)(c0 + c) * NPIX + p0 + p];
    }
  }
  __syncthreads();
  {
    int pl = tid >> 2, sub = tid & 3;
    ushort hb[16], lb[16];
    #pragma unroll
    for (int i = 0; i < 16; ++i) {
      float x = ts[(sub * 16 + i) * 65 + pl];
      ushort h = f2bf_rne(x);
      hb[i] = h;
      lb[i] = f2bf_rne(x - bf2f(h));
    }
    size_t off = (size_t)(p0 + pl) * 512 + (size_t)c0 * 2 + sub * 32;
    *(uint4*)(dst + off)            = ((uint4*)hb)[0];
    *(uint4*)(dst + off + 16)       = ((uint4*)hb)[1];
    *(uint4*)(dst + PLANE_B + off)      = ((uint4*)lb)[0];
    *(uint4*)(dst + PLANE_B + off + 16) = ((uint4*)lb)[1];
  }
}

// ---------------- kernel 1: pixel-major downsampled mask table ----------------
// mds_t[pix][f][12]: 11 objects + pad, 96 B/pixel (2.5 MB total -> L2-resident).
// Values bit-identical to m_f[o][4y][4x]; enables 3x float4 gather in k_topk.
__global__ __launch_bounds__(256) void k_mds(const float* __restrict__ m0,
                      const float* __restrict__ m1, float* __restrict__ mds_t) {
  int i = blockIdx.x * 256 + threadIdx.x;
  if (i >= NPIX) return;
  int y = i / W, x = i - (i / W) * W;
  size_t src_off = (size_t)(MD * y) * MW + MD * x;
  float vals[24];
  #pragma unroll
  for (int o = 0; o < 11; ++o) vals[o] = m0[src_off + (size_t)o * MPLANE];
  vals[11] = 0.f;
  #pragma unroll
  for (int o = 0; o < 11; ++o) vals[12 + o] = m1[src_off + (size_t)o * MPLANE];
  vals[23] = 0.f;
  float* d = mds_t + (size_t)i * 24;
  #pragma unroll
  for (int q = 0; q < 6; ++q) *(f32x4*)(d + 4 * q) = *(const f32x4*)(vals + 4 * q);
}

// ---------------- kernel 2 (MFMA, R16/R18-validated: light waves + both frames per block) ----------------
__global__ __launch_bounds__(1024, 4) void k_corr_mfma(const char* __restrict__ fqt,
                        const char* __restrict__ fm0t, const char* __restrict__ fm1t,
                        float* __restrict__ corr) {
  // bijective XCD swizzle: 210 = 8*26 + 2
  int b = blockIdx.x;
  int xcd = b & 7, idx = b >> 3;
  int wgid = (xcd < 2) ? xcd * 27 + idx : 54 + (xcd - 2) * 26 + idx;
  int yt   = wgid % NYT;
  int xt   = wgid / NYT;

  const int y0 = yt * YT;
  const int X0 = xt * XT;
  const int tid  = threadIdx.x;
  const int wv   = tid >> 6;           // wave id 0..15
  const int wyy  = wv >> 1;            // y offset in tile 0..7
  const int nt   = wv & 1;             // u group
  const int lane = tid & 63;
  const int l15  = lane & 15, l4 = lane >> 4;
  const int y    = y0 + wyy;

  __shared__ __align__(16) char bsm[2 * BUFB];   // 163840 B

  uint soff[5];
  uint ldst;
  #pragma unroll
  for (int i = 0; i < 5; ++i) {
    int gdest = wv * 64 + lane + 1024 * i;
    int ri  = gdest >> 8;          // 0..19
    int rem = gdest & 255;
    int px  = rem >> 3;            // 0..31
    int pqp = rem & 7;
    int pqs = pqp ^ (px & 7);      // source (p,q) granule (rule #21 inverse swizzle)
    int p   = pqs >> 2, q = pqs & 3;
    int r = y0 - 6 + ri;  r = (r < 0) ? 0 : (r >= H ? H - 1 : r);
    int u = X0 - 8 + px;  u = (u < 0) ? 0 : (u >= W ? W - 1 : u);
    soff[i] = (uint)((size_t)p * PLANE_B + (size_t)(r * W + u) * 512 + q * 16);
  }
  ldst = (uint)(wv * 1024 + lane * 16);

  int xA = X0 + l15;
  const char* pa = fqt + (size_t)(y * W + (xA < W ? xA : W - 1)) * 512 + l4 * 16;

  const int pxn = 16 * nt + l15;
  const uint sw  = (uint)((l15 & 7) << 4);
  const uint bh_off = (uint)((pxn * PXS +      l4 * 16) ^ sw);
  const uint bl_off = (uint)((pxn * PXS + 64 + l4 * 16) ^ sw);

  int u0 = X0 + 16 * nt + l15 - 8;
  bool uok = (u0 >= 0) && (u0 < W);

  f32x4 acc[13];
  #pragma unroll
  for (int di = 0; di < 13; ++di) acc[di] = (f32x4){0.f, 0.f, 0.f, 0.f};

  auto STAGE = [&](int buf, const char* fb, int kn) {
    #pragma unroll
    for (int i = 0; i < 5; ++i)
      __builtin_amdgcn_global_load_lds(
        (const __attribute__((address_space(1))) void*)(fb + soff[i] + kn * 64),
        (__attribute__((address_space(3))) void*)(bsm + buf * BUFB + ldst + i * 16384),
        16, 0, 0);
  };

  STAGE(0, fm0t, 0);
  uint4 aCh = *(const uint4*)(pa);
  uint4 aCl = *(const uint4*)(pa + PLANE_B);
  uint4 aNh, aNl;
  __syncthreads();   // buf0 ready

  #pragma unroll
  for (int fi = 0; fi < 2; ++fi) {
    #pragma unroll
    for (int kc = 0; kc < 8; ++kc) {
      int t = fi * 8 + kc;
      if (t < 15) {
        const char* sfb = (t < 7) ? fm0t : fm1t;   // frame of step t+1
        int kn = (kc + 1) & 7;
        STAGE((kc + 1) & 1, sfb, kn);              // flies under this step's compute
        aNh = *(const uint4*)(pa + kn * 64);
        aNl = *(const uint4*)(pa + PLANE_B + kn * 64);
      }
      const char* bb = bsm + (kc & 1) * BUFB;
      bf16x8 Ahv = __builtin_bit_cast(bf16x8, aCh);
      bf16x8 Alv = __builtin_bit_cast(bf16x8, aCl);

      #pragma unroll
      for (int di = 0; di < 13; ++di) {
        int rr = y + di - RAD;
        if (rr >= 0 && rr < H) {                   // wave-uniform
          const char* rb = bb + (wyy + di) * ROWS;
          bf16x8 Bhv = *(const bf16x8*)(rb + bh_off);
          bf16x8 Blv = *(const bf16x8*)(rb + bl_off);
          acc[di] = __builtin_amdgcn_mfma_f32_16x16x32_bf16(Ahv, Bhv, acc[di], 0, 0, 0);
          acc[di] = __builtin_amdgcn_mfma_f32_16x16x32_bf16(Ahv, Blv, acc[di], 0, 0, 0);
          acc[di] = __builtin_amdgcn_mfma_f32_16x16x32_bf16(Alv, Bhv, acc[di], 0, 0, 0);
        }
      }
      aCh = aNh; aCl = aNl;                        // static rotate
      __syncthreads();                             // vmcnt drain + barrier
    }

    float* cb = corr + (size_t)(y * W) * CW + fi * PP;
    #pragma unroll
    for (int di = 0; di < 13; ++di) {
      #pragma unroll
      for (int j = 0; j < 4; ++j) {
        int m  = l4 * 4 + j;
        int x  = X0 + m;
        int dj = 16 * nt + l15 - m - 2;
        if (x < W && dj >= 0 && dj < PATCH)
          cb[(size_t)x * CW + di * PATCH + dj] = uok ? acc[di][j] * 0.0625f : 0.f;
      }
      acc[di] = (f32x4){0.f, 0.f, 0.f, 0.f};
    }
  }
}

// ---------------- kernel 2 fallback (VALU, R2-validated) ----------------
__global__ __launch_bounds__(64) void k_corr_valu(const float* __restrict__ fq,
                       const float* __restrict__ fm0, const float* __restrict__ fm1,
                       float* __restrict__ corr) {
  int b = blockIdx.x;
  int lb = (b & 7) * 390 + (b >> 3);
  int y   = lb / 26;
  int r26 = lb - y * 26;
  int f   = r26 / 13;
  int di  = r26 - f * 13;
  const int tid = threadIdx.x;
  const int xg  = tid;
  const int r   = y + di - RAD;

  float* corr_base = corr + (size_t)(y * W) * CW + (f * PP + di * PATCH);

  if (r < 0 || r >= H) {
    if (xg < 54) {
      float* cp = corr_base + (size_t)(4 * xg) * CW;
      #pragma unroll
      for (int sub = 0; sub < 4; ++sub) {
        #pragma unroll
        for (int dj = 0; dj < PATCH; ++dj) cp[(size_t)sub * CW + dj] = 0.f;
      }
    }
    return;
  }

  const float* fm = f ? fm1 : fm0;
  __shared__ float fm_s[4 * 232];

  const float* pf[4];
  int  ldsoff[4];
  bool sval[4], mval[4];
  #pragma unroll
  for (int s = 0; s < 4; ++s) {
    int i = tid + 64 * s;
    sval[s] = (i < 232);
    int ii = sval[s] ? i : 0;
    int ch = ii / 58;
    int m  = ii - ch * 58;
    int x  = 4 * m - 8;
    mval[s] = sval[s] && (m >= 2) && (m <= 55);
    ldsoff[s] = ch * 232 + 4 * m;
    pf[s] = fm + (size_t)ch * NPIX + (size_t)r * W + (mval[s] ? x : 0);
  }

  const float* pq = fq + (size_t)y * W + 4 * ((xg < 54) ? xg : 0);

  float4 acc[PATCH];
  #pragma unroll
  for (int d = 0; d < PATCH; ++d) acc[d] = make_float4(0.f, 0.f, 0.f, 0.f);

  for (int c0 = 0; c0 < C; c0 += 4) {
    #pragma unroll
    for (int s = 0; s < 4; ++s) {
      if (sval[s]) {
        float4 v = make_float4(0.f, 0.f, 0.f, 0.f);
        if (mval[s]) v = *(const float4*)(pf[s]);
        *(float4*)&fm_s[ldsoff[s]] = v;
        pf[s] += 4 * (size_t)NPIX;
      }
    }
    __syncthreads();
    if (xg < 54) {
      #pragma unroll
      for (int ch = 0; ch < 4; ++ch) {
        float4 q4 = *(const float4*)(pq + (size_t)ch * NPIX);
        float rv[20];
        #pragma unroll
        for (int qq = 0; qq < 5; ++qq) {
          float4 t4 = *(const float4*)&fm_s[ch * 232 + 4 * xg + 4 * qq];
          rv[4*qq+0] = t4.x; rv[4*qq+1] = t4.y; rv[4*qq+2] = t4.z; rv[4*qq+3] = t4.w;
        }
        #pragma unroll
        for (int dj = 0; dj < PATCH; ++dj) {
          acc[dj].x += q4.x * rv[dj + 2];
          acc[dj].y += q4.y * rv[dj + 3];
          acc[dj].z += q4.z * rv[dj + 4];
          acc[dj].w += q4.w * rv[dj + 5];
        }
      }
      pq += 4 * (size_t)NPIX;
    }
    __syncthreads();
  }

  if (xg < 54) {
    float* cp = corr_base + (size_t)(4 * xg) * CW;
    #pragma unroll
    for (int dj = 0; dj < PATCH; ++dj) {
      cp[dj]                  = acc[dj].x * 0.0625f;
      cp[(size_t)1 * CW + dj] = acc[dj].y * 0.0625f;
      cp[(size_t)2 * CW + dj] = acc[dj].z * 0.0625f;
      cp[(size_t)3 * CW + dj] = acc[dj].w * 0.0625f;
    }
  }
}

// ---------------- kernel 3: top-36 rank select + vectorized gather (pixel-major mds) ----------------
// R18-validated selection + XCD-chunked pixel mapping; gather now 3x float4 from the
// L2-resident mds_t table (values and add order identical -> output bit-identical).
__global__ __launch_bounds__(256) void k_topk(const float* __restrict__ corr,
                       const float* __restrict__ mds_t, float* __restrict__ out) {
  int bsw = (blockIdx.x & 7) * 810 + (blockIdx.x >> 3);   // XCD-chunked remap
  int wid = bsw * 4 + (threadIdx.x >> 6);
  int lane = threadIdx.x & 63;
  if (wid >= NPIX) return;
  const float* cr = corr + (size_t)wid * CW;

  float v[6]; uint ui[6];
  #pragma unroll
  for (int s = 0; s < 6; ++s) {
    int idx = lane + 64 * s;
    bool ok = idx < 2 * PP;
    float f = ok ? cr[idx] : 0.f;
    v[s] = f;
    uint bb = __float_as_uint(f);
    uint u = bb ^ (uint)(((int)bb >> 31) | 0x80000000);
    ui[s] = ok ? u : 0u;
  }

  uint lo = 0u, hi = 0xFFFFu;
  for (int it = 0; it < 16; ++it) {
    uint mid = (lo + hi) >> 1;
    int c = 0;
    #pragma unroll
    for (int s = 0; s < 6; ++s)
      c += __popcll(__ballot((ui[s] >> 16) > mid));
    if (c <= 35) hi = mid; else lo = mid + 1;
  }
  const uint k16 = lo;

  int g = 0, e = 0;
  #pragma unroll
  for (int s = 0; s < 6; ++s) {
    g += __popcll(__ballot((ui[s] >> 16) > k16));
    e += __popcll(__ballot((ui[s] >> 16) == k16));
  }
  const int need = 36 - g;

  float w[6];
  float zp = 0.f;

  if (e == need) {
    uint x0 = k16 << 16;
    uint tb = (x0 & 0x80000000u) ? (x0 ^ 0x80000000u) : ~x0;
    const float tf = __uint_as_float(tb);
    #pragma unroll
    for (int s = 0; s < 6; ++s) {
      bool a = (ui[s] >> 16) >= k16;
      w[s] = a ? __expf(v[s] - tf) : 0.f;
      zp += w[s];
    }
  } else {
    uint l2 = k16 << 16, h2 = (k16 << 16) | 0xFFFFu;
    for (int it = 0; it < 16; ++it) {
      uint mid = l2 + ((h2 - l2) >> 1);
      int c = 0;
      #pragma unroll
      for (int s = 0; s < 6; ++s)
        c += __popcll(__ballot(ui[s] > mid));
      if (c <= 35) h2 = mid; else l2 = mid + 1;
    }
    const uint x0 = l2;
    int cgt = 0;
    #pragma unroll
    for (int s = 0; s < 6; ++s) cgt += __popcll(__ballot(ui[s] > x0));
    const int needT = 36 - cgt;
    uint tb = (x0 & 0x80000000u) ? (x0 ^ 0x80000000u) : ~x0;
    const float tf = __uint_as_float(tb);
    int prior = 0;
    #pragma unroll
    for (int s = 0; s < 6; ++s) {
      unsigned long long tie = __ballot(ui[s] == x0);
      uint below = __builtin_amdgcn_mbcnt_hi((uint)(tie >> 32),
                    __builtin_amdgcn_mbcnt_lo((uint)tie, 0u));
      bool a = (ui[s] > x0) || ((ui[s] == x0) && ((prior + (int)below) < needT));
      prior += __popcll(tie);
      w[s] = a ? __expf(v[s] - tf) : 0.f;
      zp += w[s];
    }
  }

  float Z = zp;
  #pragma unroll
  for (int off = 32; off >= 1; off >>= 1) Z += __shfl_xor(Z, off, 64);

  int y = wid / W, x = wid - (wid / W) * W;
  float no[OBJ];
  #pragma unroll
  for (int o = 0; o < OBJ; ++o) no[o] = 0.f;
  #pragma unroll
  for (int s = 0; s < 6; ++s) {
    if (w[s] > 0.f) {
      int idx = lane + 64 * s;
      int ff = idx >= PP;
      int r = idx - ff * PP;
      int di = r / PATCH, dj = r - (r / PATCH) * PATCH;
      int yy = y + di - RAD, xx = x + dj - RAD;
      if (yy >= 0 && yy < H && xx >= 0 && xx < W) {
        const float* mb = mds_t + (size_t)(yy * W + xx) * 24 + ff * 12;
        f32x4 a0 = *(const f32x4*)(mb);
        f32x4 a1 = *(const f32x4*)(mb + 4);
        f32x4 a2 = *(const f32x4*)(mb + 8);
        float ws = w[s];
        no[0] += ws * a0[0]; no[1] += ws * a0[1]; no[2]  += ws * a0[2]; no[3]  += ws * a0[3];
        no[4] += ws * a1[0]; no[5] += ws * a1[1]; no[6]  += ws * a1[2]; no[7]  += ws * a1[3];
        no[8] += ws * a2[0]; no[9] += ws * a2[1]; no[10] += ws * a2[2];
      }
    }
  }
  float inv = 1.f / Z;
  #pragma unroll
  for (int o = 0; o < OBJ; ++o) {
    float pr = no[o];
    #pragma unroll
    for (int off = 32; off >= 1; off >>= 1) pr += __shfl_xor(pr, off, 64);
    if (lane == 0) out[(size_t)o * NPIX + wid] = pr * inv;
  }
}

extern "C" void kernel_launch(void* const* d_in, const int* in_sizes, int n_in,
                              void* d_out, int out_size, void* d_ws, size_t ws_size,
                              hipStream_t stream) {
  const float* fq  = (const float*)d_in[0];
  const float* fm0 = (const float*)d_in[1];
  const float* fm1 = (const float*)d_in[2];
  const float* m0  = (const float*)d_in[3];
  const float* m1  = (const float*)d_in[4];
  float* out = (float*)d_out;

  char* ws = (char*)d_ws;
  size_t off = 0;
  auto alloc = [&](size_t sz) { size_t o = off; off = (off + sz + 1023) & ~(size_t)1023; return o; };

  size_t corr_o = alloc((size_t)NPIX * CW * sizeof(float));
  size_t mdst_o = alloc((size_t)NPIX * 24 * sizeof(float));
  size_t fqt_o  = alloc(2 * PLANE_B);
  size_t fm0t_o = alloc(2 * PLANE_B);
  size_t fm1t_o = alloc(2 * PLANE_B);
  size_t needed = off;

  float* corr  = (float*)(ws + corr_o);
  float* mds_t = (float*)(ws + mdst_o);

  k_mds<<<(NPIX + 255) / 256, 256, 0, stream>>>(m0, m1, mds_t);

  if (ws_size >= needed) {
    char* fqt  = ws + fqt_o;
    char* fm0t = ws + fm0t_o;
    char* fm1t = ws + fm1t_o;
    dim3 gp(405, 4, 3);
    k_prep<<<gp, 256, 0, stream>>>(fq, fm0, fm1, fqt, fm0t, fm1t);
    k_corr_mfma<<<NWG2, 1024, 0, stream>>>(fqt, fm0t, fm1t, corr);
  } else {
    k_corr_valu<<<120 * 26, 64, 0, stream>>>(fq, fm0, fm1, corr);
  }

  k_topk<<<NPIX / 4, 256, 0, stream>>>(corr, mds_t, out);
}